// Round 3
// baseline (399.470 us; speedup 1.0000x reference)
//
#include <hip/hip_runtime.h>

// RelationGAT fused flash-attention, MFMA bf16 (gfx950).
// out = softmax((x@Wq^T+bq) @ (nb@Wk^T+bk)^T) @ nb @ Wv^T + bv
// bk provably drops out of softmax. Q~ = x@(Wq^T Wk) + bq^T Wk.
// R2->R3: compiler spilled ~100 VGPRs to scratch chasing 4 waves/SIMD
// (VGPR_Count=128, +49MB HBM writes). LDS caps us at 2 waves/SIMD anyway:
// pin amdgpu_waves_per_eu(2,2) for the 256-VGPR budget and restructure the
// K-loop (kh/kl one k-step live, p aliased into S) to fit without spills.

#define N_ROWS 100000
#define D      64

typedef __attribute__((ext_vector_type(8)))  short  short8;
typedef __attribute__((ext_vector_type(16))) float  f32x16;

#define MFMA32(a,b,c) __builtin_amdgcn_mfma_f32_32x32x16_bf16((a),(b),(c),0,0,0)

static __device__ __forceinline__ short f2bf(float f) {
    union { float f; unsigned u; } v; v.f = f;
    unsigned r = v.u + 0x7FFFu + ((v.u >> 16) & 1u);   // RNE
    return (short)(r >> 16);
}
static __device__ __forceinline__ float bf2f(short s) {
    union { unsigned u; float f; } v;
    v.u = ((unsigned)(unsigned short)s) << 16;
    return v.f;
}
static __device__ __forceinline__ f32x16 zero16() {
    f32x16 v;
    #pragma unroll
    for (int i = 0; i < 16; i++) v[i] = 0.f;
    return v;
}

// Online-softmax + PV update for one q-half (32 rows). S is consumed (exp'd
// in place = p). accA/accB are the two d-tiles of the agg^T accumulator.
static __device__ __forceinline__ void softmax_pv(
    f32x16& S, f32x16& accA, f32x16& accB, float& m, float& l,
    const short8 va[2][2], const int hh)
{
    float tmax = S[0];
    #pragma unroll
    for (int r = 1; r < 16; r++) tmax = fmaxf(tmax, S[r]);
    tmax = fmaxf(tmax, __shfl_xor(tmax, 32));
    const float mn = fmaxf(m, tmax);
    const float sc = __expf(m - mn);
    m = mn;
    float ps = 0.f;
    #pragma unroll
    for (int r = 0; r < 16; r++) { S[r] = __expf(S[r] - mn); ps += S[r]; }
    ps += __shfl_xor(ps, 32);
    l = l * sc + ps;
    #pragma unroll
    for (int r = 0; r < 16; r++) { accA[r] *= sc; accB[r] *= sc; }

    // P (C-layout, S^T orientation) -> B-operand frags via half-swap shuffle
    short8 pb[2];
    #pragma unroll
    for (int k2 = 0; k2 < 2; k2++) {
        #pragma unroll
        for (int t = 0; t < 4; t++) {
            float own = S[8 * k2 + 4 * hh + t];
            float snd = S[8 * k2 + 4 * (1 - hh) + t];
            float rcv = __shfl_xor(snd, 32);
            pb[k2][t]     = f2bf(hh ? rcv : own);
            pb[k2][4 + t] = f2bf(hh ? own : rcv);
        }
    }
    accA = MFMA32(va[0][0], pb[0], accA);
    accA = MFMA32(va[0][1], pb[1], accA);
    accB = MFMA32(va[1][0], pb[0], accB);
    accB = MFMA32(va[1][1], pb[1], accB);
}

// LDS map (54272 B total):
//  [0,18432)      main: sKhi[128][72] bf16   | setup: GThi[64][72]+GTlo[64][72]
//  [18432,36864)  main: sKlo[128][72] bf16   | setup/epi: per-wave sQw[32][68] f32
//  [36864,53760)  main: sVT[64][132] bf16    | (sQw slices continue into here)
//  [53760,54016)  sU[64] f32 ; [54016,54272) sBv[64] f32
__global__ __launch_bounds__(256)
__attribute__((amdgpu_waves_per_eu(2, 2)))
void attn_kernel(
    const float* __restrict__ x,  const float* __restrict__ nb,
    const float* __restrict__ Wq, const float* __restrict__ bq,
    const float* __restrict__ Wk, const float* __restrict__ Wv,
    const float* __restrict__ bv, float* __restrict__ out)
{
    __shared__ __align__(16) char smem[54272];
    short* sKhi  = (short*)smem;
    short* sKlo  = (short*)(smem + 18432);
    short* sVT   = (short*)(smem + 36864);
    float* sU    = (float*)(smem + 53760);
    float* sBv   = (float*)(smem + 54016);
    short* sGThi = (short*)smem;
    short* sGTlo = (short*)(smem + 9216);

    const int tid  = threadIdx.x;
    const int lane = tid & 63;
    const int wv   = tid >> 6;        // wave 0..3
    const int hh   = lane >> 5;       // half of wave
    const int ln   = lane & 31;
    const int blockRow0 = blockIdx.x * 256;
    const int waveRow0  = blockRow0 + wv * 64;
    float* sQw = (float*)(smem + 18432 + wv * (32 * 68 * 4));  // [32][68] f32 per wave

    // ---------- setup 1: G = Wq^T Wk -> GThi/GTlo (transposed, bf16 hi/lo); u = bq^T Wk ----------
    {
        const int e2  = tid & 63;          // i2 (column of G, row of GT)
        const int e1g = wv * 16;           // wave-uniform group of i1
        float acc[16];
        #pragma unroll
        for (int q = 0; q < 16; q++) acc[q] = 0.f;
        for (int w = 0; w < 64; w++) {
            float kvv = Wk[w * 64 + e2];
            #pragma unroll
            for (int q = 0; q < 16; q++)
                acc[q] = fmaf(Wq[w * 64 + e1g + q], kvv, acc[q]);
        }
        short8 h0, h1, l0, l1;
        #pragma unroll
        for (int i = 0; i < 8; i++) {
            short a = f2bf(acc[i]);     h0[i] = a; l0[i] = f2bf(acc[i]   - bf2f(a));
            short b = f2bf(acc[8 + i]); h1[i] = b; l1[i] = f2bf(acc[8+i] - bf2f(b));
        }
        *(short8*)(sGThi + e2 * 72 + e1g)     = h0;
        *(short8*)(sGThi + e2 * 72 + e1g + 8) = h1;
        *(short8*)(sGTlo + e2 * 72 + e1g)     = l0;
        *(short8*)(sGTlo + e2 * 72 + e1g + 8) = l1;
        if (tid < 64) {
            float uu = 0.f;
            for (int w = 0; w < 64; w++) uu = fmaf(bq[w], Wk[w * 64 + tid], uu);
            sU[tid]  = uu;
            sBv[tid] = bv[tid];
        }
    }
    __syncthreads();

    // ---------- setup 2: Q~ = x.G + u via MFMA; build per-wave q-frags (hi/lo) ----------
    short8 qhi[2][4], qlo[2][4];   // [q-half of wave's 64 rows][kstep]
    #pragma unroll 1
    for (int mt = 0; mt < 2; mt++) {
        int row = waveRow0 + mt * 32 + ln;
        if (row > N_ROWS - 1) row = N_ROWS - 1;
        f32x16 Cq0 = zero16(), Cq1 = zero16();
        #pragma unroll
        for (int ks = 0; ks < 4; ks++) {
            const float* xp = x + (size_t)row * 64 + ks * 16 + hh * 8;
            float a[8];
            *(float4*)(a)     = *(const float4*)(xp);
            *(float4*)(a + 4) = *(const float4*)(xp + 4);
            short8 xhi, xlo;
            #pragma unroll
            for (int i = 0; i < 8; i++) {
                short h = f2bf(a[i]); xhi[i] = h; xlo[i] = f2bf(a[i] - bf2f(h));
            }
            short8 g0h = *(const short8*)(sGThi + (0 * 32 + ln) * 72 + ks * 16 + hh * 8);
            short8 g0l = *(const short8*)(sGTlo + (0 * 32 + ln) * 72 + ks * 16 + hh * 8);
            short8 g1h = *(const short8*)(sGThi + (1 * 32 + ln) * 72 + ks * 16 + hh * 8);
            short8 g1l = *(const short8*)(sGTlo + (1 * 32 + ln) * 72 + ks * 16 + hh * 8);
            Cq0 = MFMA32(xhi, g0h, Cq0); Cq0 = MFMA32(xlo, g0h, Cq0); Cq0 = MFMA32(xhi, g0l, Cq0);
            Cq1 = MFMA32(xhi, g1h, Cq1); Cq1 = MFMA32(xlo, g1h, Cq1); Cq1 = MFMA32(xhi, g1l, Cq1);
        }
        // scatter C (rows = x-rows local, cols = d) into this wave's sQw slice [32][68]
        #pragma unroll
        for (int r = 0; r < 16; r++) {
            int rp = (r & 3) + 8 * (r >> 2) + 4 * hh;
            sQw[rp * 68 + 0 * 32 + ln] = Cq0[r];
            sQw[rp * 68 + 1 * 32 + ln] = Cq1[r];
        }
        __builtin_amdgcn_s_waitcnt(0);  // drain LDS writes (same wave RAW)
        // read back as B-operand frags for q-rows (n = ln), add u
        #pragma unroll
        for (int ks = 0; ks < 4; ks++) {
            const float* qp = sQw + ln * 68 + ks * 16 + hh * 8;
            #pragma unroll
            for (int i = 0; i < 8; i++) {
                float val = qp[i] + sU[ks * 16 + hh * 8 + i];
                short h = f2bf(val);
                qhi[mt][ks][i] = h;
                qlo[mt][ks][i] = f2bf(val - bf2f(h));
            }
        }
    }
    __syncthreads();

    // ---------- main flash loop over M=1024 in 8 stages of 128 ----------
    f32x16 acc[2][2];          // [d-tile][q-half]  (agg^T C-frags)
    acc[0][0] = zero16(); acc[0][1] = zero16();
    acc[1][0] = zero16(); acc[1][1] = zero16();
    float mst[2] = { -3.0e38f, -3.0e38f };
    float lst[2] = { 0.f, 0.f };

    #pragma unroll 1
    for (int st = 0; st < 8; st++) {
        // stage khi/klo (j-major) and VT (d-major transpose of hi)
        {
            int jl = tid >> 1;
            int dh = (tid & 1) * 32;
            const float* np = nb + (size_t)(st * 128 + jl) * 64 + dh;
            #pragma unroll
            for (int u = 0; u < 8; u++) {
                float4 v = *(const float4*)(np + u * 4);
                float a[4] = { v.x, v.y, v.z, v.w };
                short hi4[4], lo4[4];
                #pragma unroll
                for (int e = 0; e < 4; e++) {
                    hi4[e] = f2bf(a[e]);
                    lo4[e] = f2bf(a[e] - bf2f(hi4[e]));
                }
                uint2 wh, wl;
                wh.x = (unsigned short)hi4[0] | ((unsigned)(unsigned short)hi4[1] << 16);
                wh.y = (unsigned short)hi4[2] | ((unsigned)(unsigned short)hi4[3] << 16);
                wl.x = (unsigned short)lo4[0] | ((unsigned)(unsigned short)lo4[1] << 16);
                wl.y = (unsigned short)lo4[2] | ((unsigned)(unsigned short)lo4[3] << 16);
                *((uint2*)(sKhi + jl * 72 + dh + u * 4)) = wh;
                *((uint2*)(sKlo + jl * 72 + dh + u * 4)) = wl;
                #pragma unroll
                for (int e = 0; e < 4; e++)
                    sVT[(dh + u * 4 + e) * 132 + jl] = hi4[e];
            }
        }
        __syncthreads();

        #pragma unroll 1
        for (int jc = 0; jc < 4; jc++) {
            // scores for both q-halves, one k-step of kh/kl live at a time
            const short* kb = sKhi + (jc * 32 + ln) * 72 + hh * 8;
            const short* lb = sKlo + (jc * 32 + ln) * 72 + hh * 8;
            f32x16 S0 = zero16(), S1 = zero16();
            #pragma unroll
            for (int ks = 0; ks < 4; ks++) {
                short8 kh = *(const short8*)(kb + ks * 16);
                short8 kl = *(const short8*)(lb + ks * 16);
                S0 = MFMA32(kh, qhi[0][ks], S0);
                S1 = MFMA32(kh, qhi[1][ks], S1);
                S0 = MFMA32(kl, qhi[0][ks], S0);
                S1 = MFMA32(kl, qhi[1][ks], S1);
                S0 = MFMA32(kh, qlo[0][ks], S0);
                S1 = MFMA32(kh, qlo[1][ks], S1);
            }
            short8 va[2][2];
            #pragma unroll
            for (int dt = 0; dt < 2; dt++)
                #pragma unroll
                for (int k2 = 0; k2 < 2; k2++)
                    va[dt][k2] = *(const short8*)(sVT + (dt * 32 + ln) * 132 + jc * 32 + k2 * 16 + hh * 8);

            softmax_pv(S0, acc[0][0], acc[1][0], mst[0], lst[0], va, hh);
            softmax_pv(S1, acc[0][1], acc[1][1], mst[1], lst[1], va, hh);
        }
        __syncthreads();
    }

    // ---------- epilogue: out = (agg/l) @ Wv^T + bv ----------
    float rl[2] = { 1.f / lst[0], 1.f / lst[1] };
    short8 wvf[2][4];
    #pragma unroll
    for (int mt = 0; mt < 2; mt++)
        #pragma unroll
        for (int ks = 0; ks < 4; ks++) {
            const float* wp = Wv + (size_t)(mt * 32 + ln) * 64 + ks * 16 + hh * 8;
            #pragma unroll
            for (int i = 0; i < 8; i++) wvf[mt][ks][i] = f2bf(wp[i]);
        }
    f32x16 o[2][2];
    o[0][0] = zero16(); o[0][1] = zero16(); o[1][0] = zero16(); o[1][1] = zero16();
    #pragma unroll
    for (int nt = 0; nt < 2; nt++) {
        short8 pe[4];
        #pragma unroll
        for (int ks = 0; ks < 4; ks++) {
            int dt = ks >> 1, k2 = ks & 1;
            #pragma unroll
            for (int t = 0; t < 4; t++) {
                float own = acc[dt][nt][8 * k2 + 4 * hh + t] * rl[nt];
                float snd = acc[dt][nt][8 * k2 + 4 * (1 - hh) + t] * rl[nt];
                float rcv = __shfl_xor(snd, 32);
                pe[ks][t]     = f2bf(hh ? rcv : own);
                pe[ks][4 + t] = f2bf(hh ? own : rcv);
            }
        }
        #pragma unroll
        for (int mt = 0; mt < 2; mt++)
            #pragma unroll
            for (int ks = 0; ks < 4; ks++)
                o[mt][nt] = MFMA32(wvf[mt][ks], pe[ks], o[mt][nt]);
    }
    #pragma unroll
    for (int mt = 0; mt < 2; mt++)
        #pragma unroll
        for (int nt = 0; nt < 2; nt++)
            #pragma unroll
            for (int r = 0; r < 16; r++)
                o[mt][nt][r] += sBv[mt * 32 + (r & 3) + 8 * (r >> 2) + 4 * hh];

    __syncthreads();   // all waves done with sKlo/sVT before sQw reuse
    #pragma unroll 1
    for (int nt = 0; nt < 2; nt++) {
        // transpose via per-wave LDS slice: sQw[q-local][dout]
        #pragma unroll
        for (int r = 0; r < 16; r++) {
            int rp = (r & 3) + 8 * (r >> 2) + 4 * hh;
            sQw[ln * 68 + 0 * 32 + rp] = o[0][nt][r];
            sQw[ln * 68 + 1 * 32 + rp] = o[1][nt][r];
        }
        __builtin_amdgcn_s_waitcnt(0);
        #pragma unroll
        for (int rr = 0; rr < 8; rr++) {
            int rloc = rr * 4 + (lane >> 4);
            int grow = waveRow0 + nt * 32 + rloc;
            if (grow < N_ROWS) {
                float4 vv = *(const float4*)(sQw + rloc * 68 + (lane & 15) * 4);
                *(float4*)(out + (size_t)grow * 64 + (lane & 15) * 4) = vv;
            }
        }
        __syncthreads();   // wave-slices reused across nt rounds; keep waves in step
    }
}

extern "C" void kernel_launch(void* const* d_in, const int* in_sizes, int n_in,
                              void* d_out, int out_size, void* d_ws, size_t ws_size,
                              hipStream_t stream)
{
    const float* x  = (const float*)d_in[0];
    const float* nb = (const float*)d_in[1];
    const float* Wq = (const float*)d_in[2];
    const float* bq = (const float*)d_in[3];
    const float* Wk = (const float*)d_in[4];
    // d_in[5] = bk: provably cancels in softmax (per-row constant) -> unused
    const float* Wv = (const float*)d_in[6];
    const float* bv = (const float*)d_in[7];
    float* out = (float*)d_out;

    const int grid = (N_ROWS + 255) / 256;   // 391
    attn_kernel<<<grid, 256, 0, stream>>>(x, nb, Wq, bq, Wk, Wv, bv, out);
}

// Round 4
// 333.610 us; speedup vs baseline: 1.1974x; 1.1974x over previous
//
#include <hip/hip_runtime.h>

// RelationGAT fused flash-attention, MFMA bf16 (gfx950).
// out = softmax((x@Wq^T+bq) @ (nb@Wk^T+bk)^T) @ nb @ Wv^T + bv
// bk provably drops out of softmax. Q~ = x@(Wq^T Wk) + bq^T Wk.
// No workspace used (R1: d_ws overflow corrupted host state).
// R3->R4: backend pins this kernel at 128 arch-VGPRs and memory-spills the
// 64-rows/wave design (~50 MB scratch writes). Redesign: 32 q-rows/wave,
// 8 waves (512 thr)/block so per-block staging amortization is unchanged.
// Live set ~115 regs -> fits 128, no spills. Epilogue writes out directly
// from C-fragments (4 consecutive douts per reg quad) - no LDS transpose.

#define N_ROWS 100000

typedef __attribute__((ext_vector_type(8)))  short  short8;
typedef __attribute__((ext_vector_type(16))) float  f32x16;

#define MFMA32(a,b,c) __builtin_amdgcn_mfma_f32_32x32x16_bf16((a),(b),(c),0,0,0)

static __device__ __forceinline__ short f2bf(float f) {
    union { float f; unsigned u; } v; v.f = f;
    unsigned r = v.u + 0x7FFFu + ((v.u >> 16) & 1u);   // RNE
    return (short)(r >> 16);
}
static __device__ __forceinline__ float bf2f(short s) {
    union { unsigned u; float f; } v;
    v.u = ((unsigned)(unsigned short)s) << 16;
    return v.f;
}
static __device__ __forceinline__ f32x16 zero16() {
    f32x16 v;
    #pragma unroll
    for (int i = 0; i < 16; i++) v[i] = 0.f;
    return v;
}

// Online-softmax + PV update for one wave's 32 q-rows. S (C-layout, S^T
// orientation: col=q, row=j-local) is consumed in place. va frags loaded
// just-in-time from vb0/vb1 to keep peak register pressure down.
static __device__ __forceinline__ void softmax_pv(
    f32x16& S, f32x16& a0, f32x16& a1, float& m, float& l,
    const short* vb0, const short* vb1, const int hh)
{
    float tmax = S[0];
    #pragma unroll
    for (int r = 1; r < 16; r++) tmax = fmaxf(tmax, S[r]);
    tmax = fmaxf(tmax, __shfl_xor(tmax, 32));
    const float mn = fmaxf(m, tmax);
    const float sc = __expf(m - mn);
    m = mn;
    float ps = 0.f;
    #pragma unroll
    for (int r = 0; r < 16; r++) { S[r] = __expf(S[r] - mn); ps += S[r]; }
    ps += __shfl_xor(ps, 32);
    l = l * sc + ps;
    #pragma unroll
    for (int r = 0; r < 16; r++) { a0[r] *= sc; a1[r] *= sc; }

    // P (C-layout) -> B-operand frags via half-swap shuffle
    short8 pb[2];
    #pragma unroll
    for (int k2 = 0; k2 < 2; k2++) {
        #pragma unroll
        for (int t = 0; t < 4; t++) {
            float own = S[8 * k2 + 4 * hh + t];
            float snd = S[8 * k2 + 4 * (1 - hh) + t];
            float rcv = __shfl_xor(snd, 32);
            pb[k2][t]     = f2bf(hh ? rcv : own);
            pb[k2][4 + t] = f2bf(hh ? own : rcv);
        }
    }
    short8 v00 = *(const short8*)(vb0);
    short8 v01 = *(const short8*)(vb0 + 16);
    short8 v10 = *(const short8*)(vb1);
    short8 v11 = *(const short8*)(vb1 + 16);
    a0 = MFMA32(v00, pb[0], a0);
    a0 = MFMA32(v01, pb[1], a0);
    a1 = MFMA32(v10, pb[0], a1);
    a1 = MFMA32(v11, pb[1], a1);
}

// LDS map (54272 B):
//  main:  [0,18432) sKhi[128][72] | [18432,36864) sKlo[128][72]
//         [36864,53760) sVT[64][132] (all bf16)
//  setup: [0,9216) GThi[64][72] + [9216,18432) GTlo[64][72] (aliases sKhi)
//         per-wave Q~ transpose slices [32][40] f32 at wv*5120 (0..40960)
//  fixed: [53760) sU[64] f32 ; [54016) sBv[64] f32
__global__ __launch_bounds__(512, 4) void attn_kernel(
    const float* __restrict__ x,  const float* __restrict__ nb,
    const float* __restrict__ Wq, const float* __restrict__ bq,
    const float* __restrict__ Wk, const float* __restrict__ Wv,
    const float* __restrict__ bv, float* __restrict__ out)
{
    __shared__ __align__(16) char smem[54272];
    short* sKhi  = (short*)smem;
    short* sKlo  = (short*)(smem + 18432);
    short* sVT   = (short*)(smem + 36864);
    float* sU    = (float*)(smem + 53760);
    float* sBv   = (float*)(smem + 54016);
    short* sGThi = (short*)smem;
    short* sGTlo = (short*)(smem + 9216);

    const int tid  = threadIdx.x;
    const int lane = tid & 63;
    const int wv   = tid >> 6;        // wave 0..7
    const int hh   = lane >> 5;
    const int ln   = lane & 31;
    const int qrow0 = blockIdx.x * 256 + wv * 32;   // this wave's 32 q-rows

    // ---------- setup 1: G = Wq^T Wk (bf16 hi/lo, transposed); u = bq^T Wk ----------
    {
        const int e2  = tid & 63;        // column of G = row of GT
        const int e1g = wv * 8;          // wave-uniform group of 8 i1
        float g[8];
        #pragma unroll
        for (int q = 0; q < 8; q++) g[q] = 0.f;
        for (int w = 0; w < 64; w++) {
            float kvv = Wk[w * 64 + e2];
            #pragma unroll
            for (int q = 0; q < 8; q++)
                g[q] = fmaf(Wq[w * 64 + e1g + q], kvv, g[q]);
        }
        short8 h0, l0;
        #pragma unroll
        for (int i = 0; i < 8; i++) {
            short a = f2bf(g[i]); h0[i] = a; l0[i] = f2bf(g[i] - bf2f(a));
        }
        *(short8*)(sGThi + e2 * 72 + e1g) = h0;
        *(short8*)(sGTlo + e2 * 72 + e1g) = l0;
        if (tid < 64) {
            float uu = 0.f;
            for (int w = 0; w < 64; w++) uu = fmaf(bq[w], Wk[w * 64 + tid], uu);
            sU[tid]  = uu;
            sBv[tid] = bv[tid];
        }
    }
    __syncthreads();

    // ---------- setup 2: Q~ = x.G + u via MFMA (C: row=x-row-local, col=d) ----------
    f32x16 Cq[2];
    Cq[0] = zero16(); Cq[1] = zero16();
    {
        int row = qrow0 + ln;
        if (row > N_ROWS - 1) row = N_ROWS - 1;
        #pragma unroll
        for (int ks = 0; ks < 4; ks++) {
            const float* xp = x + (size_t)row * 64 + ks * 16 + hh * 8;
            float a[8];
            *(float4*)(a)     = *(const float4*)(xp);
            *(float4*)(a + 4) = *(const float4*)(xp + 4);
            short8 xhi, xlo;
            #pragma unroll
            for (int i = 0; i < 8; i++) {
                short h = f2bf(a[i]); xhi[i] = h; xlo[i] = f2bf(a[i] - bf2f(h));
            }
            short8 g0h = *(const short8*)(sGThi + (0 * 32 + ln) * 72 + ks * 16 + hh * 8);
            short8 g0l = *(const short8*)(sGTlo + (0 * 32 + ln) * 72 + ks * 16 + hh * 8);
            short8 g1h = *(const short8*)(sGThi + (1 * 32 + ln) * 72 + ks * 16 + hh * 8);
            short8 g1l = *(const short8*)(sGTlo + (1 * 32 + ln) * 72 + ks * 16 + hh * 8);
            Cq[0] = MFMA32(xhi, g0h, Cq[0]); Cq[0] = MFMA32(xlo, g0h, Cq[0]); Cq[0] = MFMA32(xhi, g0l, Cq[0]);
            Cq[1] = MFMA32(xhi, g1h, Cq[1]); Cq[1] = MFMA32(xlo, g1h, Cq[1]); Cq[1] = MFMA32(xhi, g1l, Cq[1]);
        }
    }
    __syncthreads();   // GT reads done before slices overwrite the region

    // ---------- setup 3: transpose Q~ C-frags -> B-operand q-frags (hi/lo) ----------
    short8 qhi[4], qlo[4];
    {
        float* slice = (float*)(smem + wv * 5120);   // [32][40] f32, per wave
        #pragma unroll 1
        for (int dt = 0; dt < 2; dt++) {
            #pragma unroll
            for (int r = 0; r < 16; r++)
                slice[((r & 3) + 8 * (r >> 2) + 4 * hh) * 40 + ln] = Cq[dt][r];
            __builtin_amdgcn_s_waitcnt(0);   // wave-local LDS RAW
            #pragma unroll
            for (int k2 = 0; k2 < 2; k2++) {
                const int ks = dt * 2 + k2;
                const float* qp = slice + ln * 40 + k2 * 16 + hh * 8;
                #pragma unroll
                for (int i = 0; i < 8; i++) {
                    float val = qp[i] + sU[dt * 32 + k2 * 16 + hh * 8 + i];
                    short h = f2bf(val);
                    qhi[ks][i] = h;
                    qlo[ks][i] = f2bf(val - bf2f(h));
                }
            }
        }
    }
    __syncthreads();

    // ---------- main flash loop: M=1024 in 8 stages of 128 ----------
    f32x16 acc0 = zero16(), acc1 = zero16();   // agg^T C-frags, d-tiles 0/1
    float mst = -3.0e38f, lst = 0.f;

    #pragma unroll 1
    for (int st = 0; st < 8; st++) {
        // stage khi/klo (j-major) + VT (d-major transpose of hi)
        {
            const int jl = tid >> 2;             // 0..127
            const int ds = (tid & 3) * 16;       // d segment
            const float* np = nb + (size_t)(st * 128 + jl) * 64 + ds;
            #pragma unroll
            for (int u = 0; u < 4; u++) {
                float4 v = *(const float4*)(np + u * 4);
                float a[4] = { v.x, v.y, v.z, v.w };
                short hi4[4], lo4[4];
                #pragma unroll
                for (int e = 0; e < 4; e++) {
                    hi4[e] = f2bf(a[e]);
                    lo4[e] = f2bf(a[e] - bf2f(hi4[e]));
                }
                uint2 wh, wl;
                wh.x = (unsigned short)hi4[0] | ((unsigned)(unsigned short)hi4[1] << 16);
                wh.y = (unsigned short)hi4[2] | ((unsigned)(unsigned short)hi4[3] << 16);
                wl.x = (unsigned short)lo4[0] | ((unsigned)(unsigned short)lo4[1] << 16);
                wl.y = (unsigned short)lo4[2] | ((unsigned)(unsigned short)lo4[3] << 16);
                *((uint2*)(sKhi + jl * 72 + ds + u * 4)) = wh;
                *((uint2*)(sKlo + jl * 72 + ds + u * 4)) = wl;
                #pragma unroll
                for (int e = 0; e < 4; e++)
                    sVT[(ds + u * 4 + e) * 132 + jl] = hi4[e];
            }
        }
        __syncthreads();

        #pragma unroll 1
        for (int jc = 0; jc < 4; jc++) {
            const short* kb = sKhi + (jc * 32 + ln) * 72 + hh * 8;
            const short* lb = sKlo + (jc * 32 + ln) * 72 + hh * 8;
            f32x16 S = zero16();
            #pragma unroll
            for (int ks = 0; ks < 4; ks++) {
                short8 kh = *(const short8*)(kb + ks * 16);
                short8 kl = *(const short8*)(lb + ks * 16);
                S = MFMA32(kh, qhi[ks], S);
                S = MFMA32(kl, qhi[ks], S);
                S = MFMA32(kh, qlo[ks], S);
            }
            softmax_pv(S, acc0, acc1, mst, lst,
                       sVT + (0 * 32 + ln) * 132 + jc * 32 + hh * 8,
                       sVT + (1 * 32 + ln) * 132 + jc * 32 + hh * 8, hh);
        }
        __syncthreads();
    }

    // ---------- epilogue: out = (agg/l) @ Wv^T + bv, direct C-frag stores ----------
    const float rl = 1.f / lst;
    short8 pe[4];
    #pragma unroll
    for (int ks = 0; ks < 4; ks++) {
        const f32x16& ad = (ks >> 1) ? acc1 : acc0;
        const int k2 = ks & 1;
        #pragma unroll
        for (int t = 0; t < 4; t++) {
            float own = ad[8 * k2 + 4 * hh + t] * rl;
            float snd = ad[8 * k2 + 4 * (1 - hh) + t] * rl;
            float rcv = __shfl_xor(snd, 32);
            pe[ks][t]     = f2bf(hh ? rcv : own);
            pe[ks][4 + t] = f2bf(hh ? own : rcv);
        }
    }
    short8 wvf[2][4];
    #pragma unroll
    for (int mt = 0; mt < 2; mt++)
        #pragma unroll
        for (int ks = 0; ks < 4; ks++) {
            const float* wp = Wv + (size_t)(mt * 32 + ln) * 64 + ks * 16 + hh * 8;
            #pragma unroll
            for (int i = 0; i < 8; i++) wvf[mt][ks][i] = f2bf(wp[i]);
        }
    f32x16 o[2];
    o[0] = zero16(); o[1] = zero16();
    #pragma unroll
    for (int mt = 0; mt < 2; mt++)
        #pragma unroll
        for (int ks = 0; ks < 4; ks++)
            o[mt] = MFMA32(wvf[mt][ks], pe[ks], o[mt]);

    const int orow = qrow0 + ln;
    if (orow < N_ROWS) {
        #pragma unroll
        for (int mt = 0; mt < 2; mt++)
            #pragma unroll
            for (int rq = 0; rq < 4; rq++) {
                const int d0 = mt * 32 + 8 * rq + 4 * hh;
                float4 vv = make_float4(o[mt][4 * rq + 0] + sBv[d0 + 0],
                                        o[mt][4 * rq + 1] + sBv[d0 + 1],
                                        o[mt][4 * rq + 2] + sBv[d0 + 2],
                                        o[mt][4 * rq + 3] + sBv[d0 + 3]);
                *(float4*)(out + (size_t)orow * 64 + d0) = vv;
            }
    }
}

extern "C" void kernel_launch(void* const* d_in, const int* in_sizes, int n_in,
                              void* d_out, int out_size, void* d_ws, size_t ws_size,
                              hipStream_t stream)
{
    const float* x  = (const float*)d_in[0];
    const float* nb = (const float*)d_in[1];
    const float* Wq = (const float*)d_in[2];
    const float* bq = (const float*)d_in[3];
    const float* Wk = (const float*)d_in[4];
    // d_in[5] = bk: provably cancels in softmax -> unused
    const float* Wv = (const float*)d_in[6];
    const float* bv = (const float*)d_in[7];
    float* out = (float*)d_out;

    const int grid = (N_ROWS + 255) / 256;   // 391 blocks x 512 threads
    attn_kernel<<<grid, 512, 0, stream>>>(x, nb, Wq, bq, Wk, Wv, bv, out);
}

// Round 5
// 313.985 us; speedup vs baseline: 1.2723x; 1.0625x over previous
//
#include <hip/hip_runtime.h>

// RelationGAT fused flash-attention, MFMA fp16 (gfx950).
// out = softmax((x@Wq^T+bq) @ (nb@Wk^T+bk)^T) @ nb @ Wv^T + bv
// bk cancels in softmax. Q~ = x@G + u, G = Wq^T Wk, u = bq^T Wk; K=V=raw nb.
// R4->R5: backend splits unified VGPR budget ~50/50 arch/AGPR (R2:256->128,
// R4:128->64 evidence), so arch live must fit budget/2. Redesign:
//  - fp16 single-precision K/V/P/Wv + q hi/lo 2-term (halves LDS + QK MFMA)
//  - 16x16x32 MFMA, j-interleaved S tiles => S C-frag IS the PV B-frag
//    (zero cross-lane shuffles for P), XOR-swizzled sK for bank uniformity
//  - arch live ~77 fits 85 (waves_per_eu(2,3) => budget >=170, 50/50 split)

#define N_ROWS 100000

typedef __attribute__((ext_vector_type(8))) _Float16 half8;
typedef __attribute__((ext_vector_type(4))) float    f32x4;

#define MFMA16(a,b,c) __builtin_amdgcn_mfma_f32_16x16x32_f16((a),(b),(c),0,0,0)

static __device__ __forceinline__ f32x4 zero4() {
    f32x4 v = {0.f, 0.f, 0.f, 0.f};
    return v;
}

// LDS map (53760 B):
//  main:   sK  [0,18432)      fp16 [128][72], column-XOR-swizzled by (j>>3)&3
//          sVT [18432,35840)  fp16 [64][136]  (d-major transpose of nb tile)
//  setup1: sWk [0,16384) sWq [16384,32768) f32 staged weights
//  setup1b:sGh [0,9216) sGl [9216,18432)  fp16 G^T hi/lo [64][72]
//  setup2: per-wave slice [16][68] f32 at 18432 + wv*4352 (ends 53248)
//  fixed:  sU [53248,53504) f32 ; sBv [53504,53760) f32
__global__ __launch_bounds__(512)
__attribute__((amdgpu_waves_per_eu(2, 3)))
void attn_kernel(const float* __restrict__ x,  const float* __restrict__ nb,
                 const float* __restrict__ Wq, const float* __restrict__ bq,
                 const float* __restrict__ Wk, const float* __restrict__ Wv,
                 const float* __restrict__ bv, float* __restrict__ out)
{
    __shared__ __align__(16) char smem[53760];
    unsigned short* sK  = (unsigned short*)smem;              // [128][72] fp16
    unsigned short* sVT = (unsigned short*)(smem + 18432);    // [64][136] fp16
    unsigned short* sGh = (unsigned short*)smem;              // setup: GT hi
    unsigned short* sGl = (unsigned short*)(smem + 9216);     // setup: GT lo
    float* sWk = (float*)smem;                                // setup-1
    float* sWq = (float*)(smem + 16384);                      // setup-1
    float* sU  = (float*)(smem + 53248);
    float* sBv = (float*)(smem + 53504);

    const int tid  = threadIdx.x;
    const int lane = tid & 63;
    const int wv   = tid >> 6;     // wave 0..7
    const int Q    = lane >> 4;    // quad 0..3
    const int c    = lane & 15;    // col 0..15
    const int rbase = blockIdx.x * 256 + wv * 32;   // this wave's 32 q-rows

    // ---------------- setup 1: stage Wk/Wq, compute G^T hi/lo, u ----------------
    {
        const float4* wk4 = (const float4*)Wk;
        const float4* wq4 = (const float4*)Wq;
        float4* dk = (float4*)sWk;
        float4* dq = (float4*)sWq;
        dk[tid] = wk4[tid];  dk[tid + 512] = wk4[tid + 512];
        dq[tid] = wq4[tid];  dq[tid + 512] = wq4[tid + 512];
    }
    __syncthreads();
    float g[8];
    float uu = 0.f;
    {
        const int e2  = tid & 63;     // GT row (nb-embedding dim j)
        const int e1g = wv * 8;       // 8 columns (x-embedding dim i)
        #pragma unroll
        for (int q = 0; q < 8; q++) g[q] = 0.f;
        for (int w = 0; w < 64; w++) {
            float kv = sWk[w * 64 + e2];
            const float* wqp = sWq + w * 64 + e1g;
            #pragma unroll
            for (int q = 0; q < 8; q++) g[q] = fmaf(wqp[q], kv, g[q]);
        }
        if (tid < 64)
            for (int w = 0; w < 64; w++) uu = fmaf(bq[w], sWk[w * 64 + tid], uu);
    }
    __syncthreads();   // sWk/sWq dead
    {
        const int e2 = tid & 63, e1g = wv * 8;
        union { half8 h; uint4 u; } ph, pl;
        #pragma unroll
        for (int i = 0; i < 8; i++) {
            _Float16 h = (_Float16)g[i];
            ph.h[i] = h;
            pl.h[i] = (_Float16)(g[i] - (float)h);
        }
        *(uint4*)(sGh + e2 * 72 + e1g) = ph.u;
        *(uint4*)(sGl + e2 * 72 + e1g) = pl.u;
        if (tid < 64) { sU[tid] = uu; sBv[tid] = bv[tid]; }
    }
    __syncthreads();

    // ---------------- setup 2: Q~^T = G^T x^T via MFMA -> q-frags hi/lo ----------------
    half8 qh[2][2], ql[2][2];   // [qt][ks]
    {
        float* slice = (float*)(smem + 18432 + wv * 4352);   // [16][68] f32 per wave
        #pragma unroll 1
        for (int rt = 0; rt < 2; rt++) {
            int row = rbase + rt * 16 + c;
            if (row > N_ROWS - 1) row = N_ROWS - 1;
            half8 xh[2], xl[2];
            #pragma unroll
            for (int ks = 0; ks < 2; ks++) {
                const float* xp = x + (size_t)row * 64 + ks * 32 + Q * 8;
                float a[8];
                *(float4*)a       = *(const float4*)xp;
                *(float4*)(a + 4) = *(const float4*)(xp + 4);
                #pragma unroll
                for (int i = 0; i < 8; i++) {
                    _Float16 h = (_Float16)a[i];
                    xh[ks][i] = h;
                    xl[ks][i] = (_Float16)(a[i] - (float)h);
                }
            }
            #pragma unroll
            for (int mt = 0; mt < 4; mt++) {
                f32x4 Cm = zero4();
                #pragma unroll
                for (int ks = 0; ks < 2; ks++) {
                    half8 gh = *(const half8*)(sGh + (mt * 16 + c) * 72 + ks * 32 + Q * 8);
                    half8 gl = *(const half8*)(sGl + (mt * 16 + c) * 72 + ks * 32 + Q * 8);
                    Cm = MFMA16(gh, xh[ks], Cm);   // D[dout][row]
                    Cm = MFMA16(gh, xl[ks], Cm);
                    Cm = MFMA16(gl, xh[ks], Cm);
                }
                // C row = dout mt*16+4Q+r, col = x-row c -> slice[row][dout]
                *(f32x4*)(slice + c * 68 + mt * 16 + 4 * Q) = Cm;
            }
            __builtin_amdgcn_s_waitcnt(0);   // wave-local LDS RAW
            #pragma unroll
            for (int ks = 0; ks < 2; ks++) {
                const float* qp = slice + c * 68 + ks * 32 + Q * 8;
                const float* up = sU + ks * 32 + Q * 8;
                #pragma unroll
                for (int i = 0; i < 8; i++) {
                    float val = qp[i] + up[i];
                    _Float16 h = (_Float16)val;
                    qh[rt][ks][i] = h;
                    ql[rt][ks][i] = (_Float16)(val - (float)h);
                }
            }
            __builtin_amdgcn_s_waitcnt(0);
        }
    }
    __syncthreads();

    // ---------------- main flash loop: M=1024 in 8 stages of 128 ----------------
    f32x4 acc[2][4];   // [qt][dt] agg^T C-frags
    #pragma unroll
    for (int qt = 0; qt < 2; qt++)
        #pragma unroll
        for (int dt = 0; dt < 4; dt++) acc[qt][dt] = zero4();
    float mrow[2] = { -3.0e38f, -3.0e38f };
    float lrow[2] = { 0.f, 0.f };

    #pragma unroll 1
    for (int st = 0; st < 8; st++) {
        // stage sK (XOR-swizzled, j-major) + sVT (d-major)
        {
            const int jl  = tid >> 2;            // 0..127
            const int dsw = (tid & 3) * 16;      // halves
            const int xr  = ((jl >> 3) & 3) * 16;
            const float* np = nb + (size_t)(st * 128 + jl) * 64 + dsw;
            #pragma unroll
            for (int u4 = 0; u4 < 4; u4++) {
                float4 v = *(const float4*)(np + u4 * 4);
                union { _Float16 h[4]; uint2 u; } pk;
                pk.h[0] = (_Float16)v.x; pk.h[1] = (_Float16)v.y;
                pk.h[2] = (_Float16)v.z; pk.h[3] = (_Float16)v.w;
                *(uint2*)(sK + jl * 72 + ((dsw + u4 * 4) ^ xr)) = pk.u;
                unsigned short* vt = sVT + (dsw + u4 * 4) * 136 + jl;
                union { _Float16 h; unsigned short s; } e0, e1, e2, e3;
                e0.h = pk.h[0]; e1.h = pk.h[1]; e2.h = pk.h[2]; e3.h = pk.h[3];
                vt[0] = e0.s; vt[136] = e1.s; vt[272] = e2.s; vt[408] = e3.s;
            }
        }
        __syncthreads();

        #pragma unroll 1
        for (int jc = 0; jc < 4; jc++) {
            const int jb = jc * 32;
            // S tiles with interleaved j rows: tile t covers j = jb + 8Q + 4t + r
            f32x4 S[2][2];
            #pragma unroll
            for (int t = 0; t < 2; t++) {
                const int jrow = jb + 8 * (c >> 2) + (c & 3) + 4 * t;
                const int xr   = ((jrow >> 3) & 3) * 16;
                const unsigned short* kp = sK + jrow * 72;
                half8 k0 = *(const half8*)(kp + ((Q * 8) ^ xr));
                half8 k1 = *(const half8*)(kp + ((32 + Q * 8) ^ xr));
                #pragma unroll
                for (int qt = 0; qt < 2; qt++) {
                    f32x4 s = MFMA16(k0, qh[qt][0], zero4());
                    s = MFMA16(k1, qh[qt][1], s);
                    s = MFMA16(k0, ql[qt][0], s);
                    s = MFMA16(k1, ql[qt][1], s);
                    S[t][qt] = s;
                }
            }
            half8 pB[2];
            #pragma unroll
            for (int qt = 0; qt < 2; qt++) {
                float cm = fmaxf(fmaxf(fmaxf(S[0][qt][0], S[0][qt][1]),
                                       fmaxf(S[0][qt][2], S[0][qt][3])),
                                 fmaxf(fmaxf(S[1][qt][0], S[1][qt][1]),
                                       fmaxf(S[1][qt][2], S[1][qt][3])));
                cm = fmaxf(cm, __shfl_xor(cm, 16));
                cm = fmaxf(cm, __shfl_xor(cm, 32));
                const float mn = fmaxf(mrow[qt], cm);
                const float sc = __expf(mrow[qt] - mn);
                mrow[qt] = mn;
                float p[8]; float ps = 0.f;
                #pragma unroll
                for (int r = 0; r < 4; r++) { p[r] = __expf(S[0][qt][r] - mn); ps += p[r]; }
                #pragma unroll
                for (int r = 0; r < 4; r++) { p[4 + r] = __expf(S[1][qt][r] - mn); ps += p[4 + r]; }
                ps += __shfl_xor(ps, 16);
                ps += __shfl_xor(ps, 32);
                lrow[qt] = lrow[qt] * sc + ps;
                #pragma unroll
                for (int dt = 0; dt < 4; dt++)
                    #pragma unroll
                    for (int r = 0; r < 4; r++) acc[qt][dt][r] *= sc;
                // S C-frag already matches PV B-frag: i<4 from tile0, i>=4 tile1
                #pragma unroll
                for (int i = 0; i < 8; i++) pB[qt][i] = (_Float16)p[i];
            }
            #pragma unroll
            for (int dt = 0; dt < 4; dt++) {
                half8 vA = *(const half8*)(sVT + (dt * 16 + c) * 136 + jb + Q * 8);
                acc[0][dt] = MFMA16(vA, pB[0], acc[0][dt]);
                acc[1][dt] = MFMA16(vA, pB[1], acc[1][dt]);
            }
        }
        __syncthreads();
    }

    // ---------------- epilogue: out = (agg/l) @ Wv^T + bv ----------------
    #pragma unroll
    for (int qt = 0; qt < 2; qt++) {
        const float rl = 1.f / lrow[qt];
        #pragma unroll
        for (int dt = 0; dt < 4; dt++)
            #pragma unroll
            for (int r = 0; r < 4; r++) acc[qt][dt][r] *= rl;
    }
    half8 wf[4][2];
    #pragma unroll
    for (int mt = 0; mt < 4; mt++)
        #pragma unroll
        for (int ks = 0; ks < 2; ks++) {
            const float* wp = Wv + (size_t)(mt * 16 + c) * 64 + ks * 32 + Q * 8;
            #pragma unroll
            for (int i = 0; i < 8; i++) wf[mt][ks][i] = (_Float16)wp[i];
        }
    const int srcA = 32 * (Q & 1) + c;
    const int srcB = srcA + 16;
    const bool hi = (Q >> 1) & 1;
    f32x4 o[2][4];
    #pragma unroll
    for (int qt = 0; qt < 2; qt++) {
        half8 pe[2];
        #pragma unroll
        for (int ks = 0; ks < 2; ks++) {
            #pragma unroll
            for (int r = 0; r < 4; r++) {
                float a0 = __shfl(acc[qt][2 * ks + 0][r], srcA);
                float a1 = __shfl(acc[qt][2 * ks + 1][r], srcA);
                float b0 = __shfl(acc[qt][2 * ks + 0][r], srcB);
                float b1 = __shfl(acc[qt][2 * ks + 1][r], srcB);
                pe[ks][r]     = (_Float16)(hi ? a1 : a0);
                pe[ks][4 + r] = (_Float16)(hi ? b1 : b0);
            }
        }
        #pragma unroll
        for (int mt = 0; mt < 4; mt++) {
            f32x4 t = MFMA16(wf[mt][0], pe[0], zero4());
            o[qt][mt] = MFMA16(wf[mt][1], pe[1], t);
        }
    }
    #pragma unroll
    for (int qt = 0; qt < 2; qt++) {
        const int row = rbase + qt * 16 + c;
        if (row < N_ROWS) {
            #pragma unroll
            for (int mt = 0; mt < 4; mt++) {
                const float* bp = sBv + mt * 16 + 4 * Q;
                float4 vv = make_float4(o[qt][mt][0] + bp[0], o[qt][mt][1] + bp[1],
                                        o[qt][mt][2] + bp[2], o[qt][mt][3] + bp[3]);
                *(float4*)(out + (size_t)row * 64 + mt * 16 + 4 * Q) = vv;
            }
        }
    }
}

extern "C" void kernel_launch(void* const* d_in, const int* in_sizes, int n_in,
                              void* d_out, int out_size, void* d_ws, size_t ws_size,
                              hipStream_t stream)
{
    const float* x  = (const float*)d_in[0];
    const float* nb = (const float*)d_in[1];
    const float* Wq = (const float*)d_in[2];
    const float* bq = (const float*)d_in[3];
    const float* Wk = (const float*)d_in[4];
    // d_in[5] = bk: provably cancels in softmax -> unused
    const float* Wv = (const float*)d_in[6];
    const float* bv = (const float*)d_in[7];
    float* out = (float*)d_out;

    const int grid = (N_ROWS + 255) / 256;   // 391 blocks x 512 threads
    attn_kernel<<<grid, 512, 0, stream>>>(x, nb, Wq, bq, Wk, Wv, bv, out);
}

// Round 8
// 199.025 us; speedup vs baseline: 2.0071x; 1.5776x over previous
//
#include <hip/hip_runtime.h>

// RelationGAT fused flash-attention, MFMA fp16 (gfx950).
// out = softmax((x@Wq^T+bq) @ (nb@Wk^T+bk)^T) @ nb @ Wv^T + bv
// bk cancels in softmax. Q~ = x@G + u, G = Wq^T Wk, u = bq^T Wk; K=V=raw nb.
// R5 root cause of all spill rounds: `#pragma unroll 1` setup loops ->
// dynamic register-array indices -> allocas -> scratch + LDS promotion
// (R5: +65536 B LDS, 331 MB scratch writes). Fixed by full unrolling.
// R6/R7: container died 2x2 with amdgpu_waves_per_eu(3,4) -- the only
// never-before-compiled feature; suspected backend hang. Replaced with
// standard __launch_bounds__(256,3) (same intent: <=170 VGPRs, 3 blk/CU).

#define N_ROWS 100000

typedef __attribute__((ext_vector_type(8))) _Float16 half8;
typedef __attribute__((ext_vector_type(4))) float    f32x4;

#define MFMA16(a,b,c) __builtin_amdgcn_mfma_f32_16x16x32_f16((a),(b),(c),0,0,0)

static __device__ __forceinline__ f32x4 zero4() {
    f32x4 v = {0.f, 0.f, 0.f, 0.f};
    return v;
}

// LDS map (36608 B total):
//  main:   sK  [0,18432)      fp16 [128][72], rows physically permuted
//          sVT [18432,36096)  fp16 [64][138]  (d-major transpose)
//  setup1: sWk [0,16384) sWq [16384,32768) f32 staged weights
//  setup2: per-wave slice [16][68] f32 at wv*4352 (0..17408)
//          sGh [17408,26624) sGl [26624,35840) fp16 G^T hi/lo [64][72]
//  fixed:  sU [36096,36352) f32 ; sBv [36352,36608) f32
__global__ __launch_bounds__(256, 3)
void attn_kernel(const float* __restrict__ x,  const float* __restrict__ nb,
                 const float* __restrict__ Wq, const float* __restrict__ bq,
                 const float* __restrict__ Wk, const float* __restrict__ Wv,
                 const float* __restrict__ bv, float* __restrict__ out)
{
    __shared__ __align__(16) char smem[36608];
    unsigned short* sK  = (unsigned short*)smem;              // [128][72] fp16
    unsigned short* sVT = (unsigned short*)(smem + 18432);    // [64][138] fp16
    unsigned short* sGh = (unsigned short*)(smem + 17408);    // setup: GT hi
    unsigned short* sGl = (unsigned short*)(smem + 26624);    // setup: GT lo
    float* sWk = (float*)smem;                                // setup-1
    float* sWq = (float*)(smem + 16384);                      // setup-1
    float* sU  = (float*)(smem + 36096);
    float* sBv = (float*)(smem + 36352);

    const int tid  = threadIdx.x;
    const int lane = tid & 63;
    const int wv   = tid >> 6;     // wave 0..3
    const int Q    = lane >> 4;    // quad 0..3
    const int c    = lane & 15;    // col 0..15
    const int rbase = blockIdx.x * 128 + wv * 32;   // this wave's 32 q-rows

    // ---------------- setup 1: stage Wk/Wq, compute G^T hi/lo, u ----------------
    {
        const float4* wk4 = (const float4*)Wk;
        const float4* wq4 = (const float4*)Wq;
        float4* dk = (float4*)sWk;
        float4* dq = (float4*)sWq;
        #pragma unroll
        for (int u = 0; u < 4; u++) {
            dk[u * 256 + tid] = wk4[u * 256 + tid];
            dq[u * 256 + tid] = wq4[u * 256 + tid];
        }
    }
    __syncthreads();
    float g[16];
    float uu = 0.f;
    {
        const int e2  = tid & 63;        // GT row (k-embedding dim)
        const int e1g = wv * 16;         // 16 columns (x-embedding dim)
        #pragma unroll
        for (int q = 0; q < 16; q++) g[q] = 0.f;
        for (int w = 0; w < 64; w++) {
            float kv = sWk[w * 64 + e2];
            const float* wqp = sWq + w * 64 + e1g;
            #pragma unroll
            for (int q = 0; q < 16; q++) g[q] = fmaf(wqp[q], kv, g[q]);
        }
        if (tid < 64)
            for (int w = 0; w < 64; w++) uu = fmaf(bq[w], sWk[w * 64 + tid], uu);
    }
    __syncthreads();   // sWk/sWq dead
    {
        const int e2 = tid & 63, e1g = wv * 16;
        union { half8 h; uint4 u; } ph0, pl0, ph1, pl1;
        #pragma unroll
        for (int i = 0; i < 8; i++) {
            _Float16 h0 = (_Float16)g[i];
            ph0.h[i] = h0; pl0.h[i] = (_Float16)(g[i] - (float)h0);
            _Float16 h1 = (_Float16)g[8 + i];
            ph1.h[i] = h1; pl1.h[i] = (_Float16)(g[8 + i] - (float)h1);
        }
        *(uint4*)(sGh + e2 * 72 + e1g)     = ph0.u;
        *(uint4*)(sGh + e2 * 72 + e1g + 8) = ph1.u;
        *(uint4*)(sGl + e2 * 72 + e1g)     = pl0.u;
        *(uint4*)(sGl + e2 * 72 + e1g + 8) = pl1.u;
        if (tid < 64) { sU[tid] = uu; sBv[tid] = bv[tid]; }
    }
    __syncthreads();

    // ------- setup 2: Q~^T = G^T x^T via MFMA -> q-frags hi/lo (FULLY unrolled) -------
    half8 qh[2][2], ql[2][2];   // [rt][ks] -- static indices ONLY
    float* slice = (float*)(smem + wv * 4352);   // [16][68] f32 per wave
    #pragma unroll
    for (int rt = 0; rt < 2; rt++) {
        int row = rbase + rt * 16 + c;
        if (row > N_ROWS - 1) row = N_ROWS - 1;
        half8 xh[2], xl[2];
        #pragma unroll
        for (int ks = 0; ks < 2; ks++) {
            const float* xp = x + (size_t)row * 64 + ks * 32 + Q * 8;
            float a[8];
            *(float4*)a       = *(const float4*)xp;
            *(float4*)(a + 4) = *(const float4*)(xp + 4);
            #pragma unroll
            for (int i = 0; i < 8; i++) {
                _Float16 h = (_Float16)a[i];
                xh[ks][i] = h;
                xl[ks][i] = (_Float16)(a[i] - (float)h);
            }
        }
        #pragma unroll
        for (int mt = 0; mt < 4; mt++) {
            f32x4 Cm = zero4();
            #pragma unroll
            for (int ks = 0; ks < 2; ks++) {
                half8 gh = *(const half8*)(sGh + (mt * 16 + c) * 72 + ks * 32 + Q * 8);
                half8 gl = *(const half8*)(sGl + (mt * 16 + c) * 72 + ks * 32 + Q * 8);
                Cm = MFMA16(gh, xh[ks], Cm);   // D[dout][x-row]
                Cm = MFMA16(gh, xl[ks], Cm);
                Cm = MFMA16(gl, xh[ks], Cm);
            }
            // C row = dout mt*16+4Q+r, col = x-row c -> slice[x-row][dout]
            *(f32x4*)(slice + c * 68 + mt * 16 + 4 * Q) = Cm;
        }
        __builtin_amdgcn_s_waitcnt(0);   // wave-local LDS RAW
        #pragma unroll
        for (int ks = 0; ks < 2; ks++) {
            const float* qp = slice + c * 68 + ks * 32 + Q * 8;
            const float* up = sU + ks * 32 + Q * 8;
            #pragma unroll
            for (int i = 0; i < 8; i++) {
                float val = qp[i] + up[i];
                _Float16 h = (_Float16)val;
                qh[rt][ks][i] = h;
                ql[rt][ks][i] = (_Float16)(val - (float)h);
            }
        }
        __builtin_amdgcn_s_waitcnt(0);   // reads done before rt=1 overwrites slice
    }
    __syncthreads();

    // ---------------- main flash loop: M=1024 in 8 stages of 128 ----------------
    f32x4 acc[2][4];   // [qt][dt] agg^T C-frags (static idx only)
    #pragma unroll
    for (int qt = 0; qt < 2; qt++)
        #pragma unroll
        for (int dt = 0; dt < 4; dt++) acc[qt][dt] = zero4();
    float mrow[2] = { -3.0e38f, -3.0e38f };
    float lrow[2] = { 0.f, 0.f };

    #pragma unroll 1
    for (int st = 0; st < 8; st++) {
        // stage sK (row-permuted, j-major) + sVT (d-major, stride 138)
        {
            const int jl  = tid >> 1;            // 0..127 logical j in tile
            const int dsw = (tid & 1) * 32;      // d half
            // physical row: within 32-group, j=[Q1 Q0 t r1 r0] -> p=[t Q1 Q0 r1 r0]
            const int pr = (jl & ~31) | (((jl >> 2) & 1) << 4) | (((jl >> 3) & 3) << 2) | (jl & 3);
            const float* np = nb + (size_t)(st * 128 + jl) * 64 + dsw;
            #pragma unroll
            for (int u4 = 0; u4 < 8; u4++) {
                float4 v = *(const float4*)(np + u4 * 4);
                union { _Float16 h[4]; uint2 u; } pk;
                pk.h[0] = (_Float16)v.x; pk.h[1] = (_Float16)v.y;
                pk.h[2] = (_Float16)v.z; pk.h[3] = (_Float16)v.w;
                *(uint2*)(sK + pr * 72 + dsw + u4 * 4) = pk.u;
                unsigned short* vt = sVT + (dsw + u4 * 4) * 138 + jl;
                union { _Float16 h; unsigned short s; } e0, e1, e2, e3;
                e0.h = pk.h[0]; e1.h = pk.h[1]; e2.h = pk.h[2]; e3.h = pk.h[3];
                vt[0] = e0.s; vt[138] = e1.s; vt[276] = e2.s; vt[414] = e3.s;
            }
        }
        __syncthreads();

        #pragma unroll 1
        for (int jc = 0; jc < 4; jc++) {
            const int jb = jc * 32;
            // S tiles: physical rows jb+16t+c (contiguous => conflict-free);
            // logical j of S-frag lane(Q,c) reg r = jb + 8Q + 4t + r
            f32x4 S[2][2];   // [t][qt]
            #pragma unroll
            for (int t = 0; t < 2; t++) {
                const unsigned short* kp = sK + (jb + 16 * t + c) * 72;
                half8 k0 = *(const half8*)(kp + Q * 8);
                half8 k1 = *(const half8*)(kp + 32 + Q * 8);
                #pragma unroll
                for (int qt = 0; qt < 2; qt++) {
                    f32x4 s = MFMA16(k0, qh[qt][0], zero4());
                    s = MFMA16(k1, qh[qt][1], s);
                    s = MFMA16(k0, ql[qt][0], s);
                    s = MFMA16(k1, ql[qt][1], s);
                    S[t][qt] = s;
                }
            }
            half8 pB[2];
            #pragma unroll
            for (int qt = 0; qt < 2; qt++) {
                float cm = fmaxf(fmaxf(fmaxf(S[0][qt][0], S[0][qt][1]),
                                       fmaxf(S[0][qt][2], S[0][qt][3])),
                                 fmaxf(fmaxf(S[1][qt][0], S[1][qt][1]),
                                       fmaxf(S[1][qt][2], S[1][qt][3])));
                cm = fmaxf(cm, __shfl_xor(cm, 16));
                cm = fmaxf(cm, __shfl_xor(cm, 32));
                const float mn = fmaxf(mrow[qt], cm);
                const float sc = __expf(mrow[qt] - mn);
                mrow[qt] = mn;
                float p[8]; float ps = 0.f;
                #pragma unroll
                for (int r = 0; r < 4; r++) { p[r] = __expf(S[0][qt][r] - mn); ps += p[r]; }
                #pragma unroll
                for (int r = 0; r < 4; r++) { p[4 + r] = __expf(S[1][qt][r] - mn); ps += p[4 + r]; }
                ps += __shfl_xor(ps, 16);
                ps += __shfl_xor(ps, 32);
                lrow[qt] = lrow[qt] * sc + ps;
                #pragma unroll
                for (int dt = 0; dt < 4; dt++)
                    #pragma unroll
                    for (int r = 0; r < 4; r++) acc[qt][dt][r] *= sc;
                // S C-frag already matches PV B-frag (i<4 from t=0, i>=4 t=1)
                #pragma unroll
                for (int i = 0; i < 8; i++) pB[qt][i] = (_Float16)p[i];
            }
            #pragma unroll
            for (int dt = 0; dt < 4; dt++) {
                half8 vA = *(const half8*)(sVT + (dt * 16 + c) * 138 + jb + Q * 8);
                acc[0][dt] = MFMA16(vA, pB[0], acc[0][dt]);
                acc[1][dt] = MFMA16(vA, pB[1], acc[1][dt]);
            }
        }
        __syncthreads();
    }

    // ---------------- epilogue: out = (agg/l) @ Wv^T + bv ----------------
    #pragma unroll
    for (int qt = 0; qt < 2; qt++) {
        const float rl = 1.f / lrow[qt];
        #pragma unroll
        for (int dt = 0; dt < 4; dt++)
            #pragma unroll
            for (int r = 0; r < 4; r++) acc[qt][dt][r] *= rl;
    }
    half8 wf[4][2];
    #pragma unroll
    for (int mt = 0; mt < 4; mt++)
        #pragma unroll
        for (int ks = 0; ks < 2; ks++) {
            const float* wp = Wv + (size_t)(mt * 16 + c) * 64 + ks * 32 + Q * 8;
            #pragma unroll
            for (int i = 0; i < 8; i++) wf[mt][ks][i] = (_Float16)wp[i];
        }
    const int srcA = 32 * (Q & 1) + c;
    const int srcB = srcA + 16;
    const bool hi = (Q >> 1) & 1;
    f32x4 o[2][4];
    #pragma unroll
    for (int qt = 0; qt < 2; qt++) {
        half8 pe[2];
        #pragma unroll
        for (int ks = 0; ks < 2; ks++) {
            #pragma unroll
            for (int r = 0; r < 4; r++) {
                float a0 = __shfl(acc[qt][2 * ks + 0][r], srcA);
                float a1 = __shfl(acc[qt][2 * ks + 1][r], srcA);
                float b0 = __shfl(acc[qt][2 * ks + 0][r], srcB);
                float b1 = __shfl(acc[qt][2 * ks + 1][r], srcB);
                pe[ks][r]     = (_Float16)(hi ? a1 : a0);
                pe[ks][4 + r] = (_Float16)(hi ? b1 : b0);
            }
        }
        #pragma unroll
        for (int mt = 0; mt < 4; mt++) {
            f32x4 t = MFMA16(wf[mt][0], pe[0], zero4());
            o[qt][mt] = MFMA16(wf[mt][1], pe[1], t);
        }
    }
    #pragma unroll
    for (int qt = 0; qt < 2; qt++) {
        const int row = rbase + qt * 16 + c;
        if (row < N_ROWS) {
            #pragma unroll
            for (int mt = 0; mt < 4; mt++) {
                const float* bp = sBv + mt * 16 + 4 * Q;
                float4 vv = make_float4(o[qt][mt][0] + bp[0], o[qt][mt][1] + bp[1],
                                        o[qt][mt][2] + bp[2], o[qt][mt][3] + bp[3]);
                *(float4*)(out + (size_t)row * 64 + mt * 16 + 4 * Q) = vv;
            }
        }
    }
}

extern "C" void kernel_launch(void* const* d_in, const int* in_sizes, int n_in,
                              void* d_out, int out_size, void* d_ws, size_t ws_size,
                              hipStream_t stream)
{
    const float* x  = (const float*)d_in[0];
    const float* nb = (const float*)d_in[1];
    const float* Wq = (const float*)d_in[2];
    const float* bq = (const float*)d_in[3];
    const float* Wk = (const float*)d_in[4];
    // d_in[5] = bk: provably cancels in softmax -> unused
    const float* Wv = (const float*)d_in[6];
    const float* bv = (const float*)d_in[7];
    float* out = (float*)d_out;

    const int grid = (N_ROWS + 127) / 128;   // 782 blocks x 256 threads
    attn_kernel<<<grid, 256, 0, stream>>>(x, nb, Wq, bq, Wk, Wv, bv, out);
}